// Round 8
// baseline (131.622 us; speedup 1.0000x reference)
//
#include <hip/hip_runtime.h>

// DistNet: out[n] = sigmoid((min_p ||x_n - p||^2 + alpha) / beta)
// beta = softplus(beta_raw), alpha = -beta*ln(1000)
// x: [65536,128] f32, points: [2048,128] f32, beta_raw: [1] f32, out: [65536] f32
//
// R8 design: R7's wave-private barrier-free staging, register-sized to fit.
// Block = 64 rows x 2048 pts, 4 waves; each wave owns ALL 64 rows (4 A-tiles,
// 32 VGPR fp8) x a PRIVATE 512-pt partition staged via global_load_lds into
// its own LDS region -- no __syncthreads in the K-loop, only wave-local
// s_waitcnt vmcnt(0) lgkmcnt(0). R7's 8-tile version spilled (WRITE_SIZE
// 256KB->11MB scratch); 4 tiles keeps ~90 VGPRs. 128-pt stages (41 KB LDS)
// -> 3 blocks/CU for cross-block cover of the wave-local drains.
// fp8 e4m3 mfma_scale_f32_16x16x128 (K=128 in one MFMA, scales=1.0).

#define NROWS 65536
#define NPTS  2048
#define DIMS  128
#define LOG1000F 6.9077542789816375f
#define STAGE_PTS 128
#define NSTAGES (NPTS / STAGE_PTS)   // 16

typedef __attribute__((ext_vector_type(8))) int i32x8;
typedef __attribute__((ext_vector_type(4))) float f32x4;

union AFrag { int d[8]; i32x8 v; };
union BFrag { uint4 u4[2]; i32x8 v; };

// --- pre-kernel: points f32 -> fp8 e4m3 in ws, plus ||p||^2 -----------------
__global__ __launch_bounds__(256) void prep_points_kernel(
    const float* __restrict__ pts, unsigned char* __restrict__ ptsf8,
    float* __restrict__ pnorm)
{
    int tid  = threadIdx.x;
    int lane = tid & 63;
    int w    = tid >> 6;
    int pt   = blockIdx.x * 4 + w;            // one wave per point
    const float2 v = *reinterpret_cast<const float2*>(
        pts + (size_t)pt * DIMS + lane * 2);  // 2 features per lane
    int pk = __builtin_amdgcn_cvt_pk_fp8_f32(v.x, v.y, 0, false);
    *reinterpret_cast<unsigned short*>(ptsf8 + (size_t)pt * DIMS + lane * 2) =
        (unsigned short)(pk & 0xFFFF);
    float ss = v.x * v.x + v.y * v.y;
    ss += __shfl_xor(ss, 1, 64);
    ss += __shfl_xor(ss, 2, 64);
    ss += __shfl_xor(ss, 4, 64);
    ss += __shfl_xor(ss, 8, 64);
    ss += __shfl_xor(ss, 16, 64);
    ss += __shfl_xor(ss, 32, 64);
    if (lane == 0) pnorm[pt] = ss;
}

// --- main kernel ------------------------------------------------------------
// grid: NROWS/64 = 1024 blocks x 256 threads (4 waves); block owns 64 rows;
// wave owns all 64 rows x a 512-point partition.
__global__ __launch_bounds__(256, 3) void distnet_main_kernel(
    const float* __restrict__ x, const unsigned char* __restrict__ ptsf8,
    const float* __restrict__ pnorm, const float* __restrict__ beta_raw,
    float* __restrict__ out)
{
    // stage: 128 pts x 128 B = 16 KB; unit (tt*2+c)*64 + lane (16 B each);
    // wave w's private region: tt in {2w, 2w+1} -- disjoint across waves.
    __shared__ uint4 s_b[2][STAGE_PTS * DIMS / 16];   // 2 x 16 KB
    __shared__ float s_pn[NPTS];                      // 8 KB
    __shared__ float s_xn[64];                        // block row norms
    __shared__ float s_part[4 * 64];                  // 1 KB partial mins

    int tid  = threadIdx.x;
    int wave = tid >> 6;
    int lane = tid & 63;
    int m    = lane & 15;          // A row / B col (point) index
    int q    = lane >> 4;          // k-quad: lane covers k = q*32 .. q*32+31
    int r0   = blockIdx.x * 64;    // block base row

    // Async staging of wave-private tiles: wave w stages tiles {2w, 2w+1},
    // halves c=0,1 -> 4 x 1KB loads. Lane src: p = s*128 + tt*16 + m,
    // byte = p*128 + q*32 + c*16. LDS dst: uniform &s_b[buf][(tt*2+c)*64].
    const unsigned char* gbase = ptsf8;
    auto issue_stage = [&](int s, int buf) {
#pragma unroll
        for (int i = 0; i < 4; ++i) {
            int tt = wave * 2 + (i >> 1);
            int c  = i & 1;
            size_t pbyte = (size_t)(s * STAGE_PTS + tt * 16 + m) * DIMS
                           + (size_t)q * 32 + (size_t)c * 16;
            const void* g = gbase + pbyte;
            void* l = (void*)&s_b[buf][(tt * 2 + c) * 64];
            __builtin_amdgcn_global_load_lds(
                (const __attribute__((address_space(1))) unsigned int*)g,
                (__attribute__((address_space(3))) unsigned int*)l,
                16, 0, 0);
        }
    };

    issue_stage(0, 0);   // overlap with A-frag setup below

    for (int i = tid; i < NPTS / 4; i += 256)
        *reinterpret_cast<float4*>(&s_pn[i * 4]) =
            reinterpret_cast<const float4*>(pnorm)[i];

    // A fragments: 4 row-tiles (all 64 block rows); lane holds
    // A[m][k=q*32+j], j=0..31 (32 B fp8 = 8 VGPRs per tile).
    AFrag afrag[4];
#pragma unroll
    for (int t = 0; t < 4; ++t) {
        const float* xp = x + (size_t)(r0 + t * 16 + m) * DIMS + q * 32;
        float ss = 0.f;
#pragma unroll
        for (int d = 0; d < 8; ++d) {
            float4 v = *reinterpret_cast<const float4*>(xp + d * 4);
            int w0 = __builtin_amdgcn_cvt_pk_fp8_f32(v.x, v.y, 0, false);
            w0 = __builtin_amdgcn_cvt_pk_fp8_f32(v.z, v.w, w0, true);
            afrag[t].d[d] = w0;
            ss += v.x * v.x + v.y * v.y + v.z * v.z + v.w * v.w;
        }
        ss += __shfl_xor(ss, 16, 64);
        ss += __shfl_xor(ss, 32, 64);
        if (wave == 0 && lane < 16) s_xn[t * 16 + lane] = ss;
    }
    __syncthreads();   // s_pn / s_xn ready (stage-0 loads are wave-private)

    // runmin tracks min over this wave's points of (||p||^2 - 2 x.p).
    float runmin[4][4];
#pragma unroll
    for (int t = 0; t < 4; ++t)
#pragma unroll
        for (int r = 0; r < 4; ++r) runmin[t][r] = 1e30f;

    for (int s = 0; s < NSTAGES; ++s) {
        // Wave-local drain: stage-s loads done (vmcnt) AND all ds_reads of
        // the buffer about to be overwritten have returned (lgkmcnt).
        __builtin_amdgcn_s_waitcnt(0x0070);   // vmcnt(0) lgkmcnt(0)
        if (s + 1 < NSTAGES) issue_stage(s + 1, (s + 1) & 1);

        const uint4* bbuf = &s_b[s & 1][0];
#pragma unroll
        for (int tl = 0; tl < 2; ++tl) {
            int tt = wave * 2 + tl;
            BFrag bf;
            bf.u4[0] = bbuf[(tt * 2 + 0) * 64 + lane];   // ds_read_b128
            bf.u4[1] = bbuf[(tt * 2 + 1) * 64 + lane];
            float pn = s_pn[s * STAGE_PTS + tt * 16 + m]; // ds_read_b32
#pragma unroll
            for (int t = 0; t < 4; ++t) {
                f32x4 acc = {0.f, 0.f, 0.f, 0.f};
                acc = __builtin_amdgcn_mfma_scale_f32_16x16x128_f8f6f4(
                    afrag[t].v, bf.v, acc, 0, 0, 0,
                    0x7F7F7F7F, 0, 0x7F7F7F7F);
#pragma unroll
                for (int r = 0; r < 4; ++r)
                    runmin[t][r] = fminf(runmin[t][r],
                                         fmaf(-2.f, acc[r], pn));
            }
        }
    }

    // Per-wave lane reduce (min over the 16 cols), write partials to LDS.
    // C/D layout: col = m, row_local = t*16 + q*4 + r.
#pragma unroll
    for (int t = 0; t < 4; ++t) {
#pragma unroll
        for (int r = 0; r < 4; ++r) {
            float v = runmin[t][r];
            v = fminf(v, __shfl_xor(v, 1, 64));
            v = fminf(v, __shfl_xor(v, 2, 64));
            v = fminf(v, __shfl_xor(v, 4, 64));
            v = fminf(v, __shfl_xor(v, 8, 64));
            if (m == 0) s_part[wave * 64 + t * 16 + q * 4 + r] = v;
        }
    }
    __syncthreads();

    // Combine the 4 wave partitions, finish d^2, sigmoid, store.
    if (tid < 64) {
        float v = fminf(fminf(s_part[tid], s_part[64 + tid]),
                        fminf(s_part[128 + tid], s_part[192 + tid]));
        float xnv = s_xn[tid];
        float d2  = fmaxf(xnv + v, 0.f);
        float br    = beta_raw[0];
        float beta  = log1pf(expf(br));
        float alpha = -beta * LOG1000F;
        float z = (d2 + alpha) / beta;
        out[r0 + tid] = 1.f / (1.f + expf(-z));
    }
}

extern "C" void kernel_launch(void* const* d_in, const int* in_sizes, int n_in,
                              void* d_out, int out_size, void* d_ws, size_t ws_size,
                              hipStream_t stream) {
    const float* x        = (const float*)d_in[0];
    const float* pts      = (const float*)d_in[1];
    const float* beta_raw = (const float*)d_in[2];
    float* out            = (float*)d_out;

    unsigned char* ptsf8 = (unsigned char*)d_ws;                    // 256 KB
    float* pnorm = (float*)((char*)d_ws + (size_t)NPTS * DIMS);     // 8 KB

    prep_points_kernel<<<NPTS / 4, 256, 0, stream>>>(pts, ptsf8, pnorm);
    distnet_main_kernel<<<NROWS / 64, 256, 0, stream>>>(x, ptsf8, pnorm,
                                                        beta_raw, out);
}

// Round 9
// 112.382 us; speedup vs baseline: 1.1712x; 1.1712x over previous
//
#include <hip/hip_runtime.h>

// DistNet: out[n] = sigmoid((min_p ||x_n - p||^2 + alpha) / beta)
// beta = softplus(beta_raw), alpha = -beta*ln(1000)
// x: [65536,128] f32, points: [2048,128] f32, beta_raw: [1] f32, out: [65536] f32
//
// R9 design: NO staged loop. Block = 256 rows x 512-point partition; the
// 64 KB fp8 B-quarter is loaded into LDS once (global_load_lds prologue,
// ONE barrier), then a barrier-free drain-free K-loop: 32 pt-tiles x
// (2 ds_read_b128 + 4 MFMA + fmin). Wave = 64 rows (4 A-tiles, ~48 regs of
// A+min state -- R8 measured 76 VGPR for this shape, no spill). Partition
// mins combined across the 4 point-quarter blocks via uint atomicMin
// (d^2 >= 0 so float order == uint order); sigmoid in a tiny finish kernel.
// 1024 blocks, 68.5 KB LDS -> 2 blocks/CU. fp8 mfma_scale 16x16x128.

#define NROWS 65536
#define NPTS  2048
#define DIMS  128
#define LOG1000F 6.9077542789816375f
#define RPB 256                  // rows per block
#define PPB 512                  // points per block
#define TPB (PPB / 16)           // 32 pt-tiles per block

typedef __attribute__((ext_vector_type(8))) int i32x8;
typedef __attribute__((ext_vector_type(4))) float f32x4;

union AFrag { int d[8]; i32x8 v; };
union BFrag { uint4 u4[2]; i32x8 v; };

// --- pre-kernel: points f32 -> fp8 e4m3, ||p||^2, and min-ws init -----------
__global__ __launch_bounds__(256) void prep_points_kernel(
    const float* __restrict__ pts, unsigned char* __restrict__ ptsf8,
    float* __restrict__ pnorm, unsigned int* __restrict__ minws)
{
    int tid  = threadIdx.x;
    int gid  = blockIdx.x * 256 + tid;
    if (gid < NROWS) minws[gid] = 0x7F800000u;   // +inf (re-init every launch)

    int lane = tid & 63;
    int w    = tid >> 6;
    int pt   = blockIdx.x * 4 + w;            // one wave per point
    const float2 v = *reinterpret_cast<const float2*>(
        pts + (size_t)pt * DIMS + lane * 2);  // 2 features per lane
    int pk = __builtin_amdgcn_cvt_pk_fp8_f32(v.x, v.y, 0, false);
    *reinterpret_cast<unsigned short*>(ptsf8 + (size_t)pt * DIMS + lane * 2) =
        (unsigned short)(pk & 0xFFFF);
    float ss = v.x * v.x + v.y * v.y;
    ss += __shfl_xor(ss, 1, 64);
    ss += __shfl_xor(ss, 2, 64);
    ss += __shfl_xor(ss, 4, 64);
    ss += __shfl_xor(ss, 8, 64);
    ss += __shfl_xor(ss, 16, 64);
    ss += __shfl_xor(ss, 32, 64);
    if (lane == 0) pnorm[pt] = ss;
}

// --- main kernel ------------------------------------------------------------
// grid: (NROWS/RPB) * (NPTS/PPB) = 256 * 4 = 1024 blocks x 256 threads.
// block b: row-group b>>2, point-quarter b&3. Wave owns 64 rows x all 512 pts.
__global__ __launch_bounds__(256, 2) void distnet_main_kernel(
    const float* __restrict__ x, const unsigned char* __restrict__ ptsf8,
    const float* __restrict__ pnorm, unsigned int* __restrict__ minws)
{
    // B quarter in fragment order: 16B unit (tt*2+c)*64 + lane
    __shared__ uint4 s_b[PPB * DIMS / 16];   // 64 KB
    __shared__ float s_pn[PPB];              // 2 KB
    __shared__ float s_xn[RPB];              // 1 KB

    int tid  = threadIdx.x;
    int wave = tid >> 6;
    int lane = tid & 63;
    int m    = lane & 15;          // A row / B col (point) index
    int q    = lane >> 4;          // k-quad: lane covers k = q*32 .. q*32+31
    int rg   = blockIdx.x >> 2;
    int ph   = blockIdx.x & 3;
    int r0   = rg * RPB;
    int p0   = ph * PPB;

    // Prologue: load the whole B quarter into LDS. Wave w loads pt-tiles
    // tt in [w*8, w*8+8), halves c=0,1 -> 16 x 1KB global_load_lds.
    // Lane src: p = p0 + tt*16 + m, byte = p*128 + q*32 + c*16.
    const unsigned char* gbase = ptsf8;
#pragma unroll
    for (int i = 0; i < 16; ++i) {
        int tt = wave * 8 + (i >> 1);
        int c  = i & 1;
        size_t pbyte = (size_t)(p0 + tt * 16 + m) * DIMS
                       + (size_t)q * 32 + (size_t)c * 16;
        const void* g = gbase + pbyte;
        void* l = (void*)&s_b[(tt * 2 + c) * 64];
        __builtin_amdgcn_global_load_lds(
            (const __attribute__((address_space(1))) unsigned int*)g,
            (__attribute__((address_space(3))) unsigned int*)l,
            16, 0, 0);
    }
    // s_pn: 512 floats = 256 threads x float2
    {
        float2 v = reinterpret_cast<const float2*>(pnorm + p0)[tid];
        reinterpret_cast<float2*>(s_pn)[tid] = v;
    }

    // A fragments: 4 row-tiles (wave's 64 rows); lane holds A[m][k=q*32+j],
    // j=0..31 (32 B fp8 = 8 VGPRs per tile). Overlaps the async B loads.
    AFrag afrag[4];
#pragma unroll
    for (int t = 0; t < 4; ++t) {
        const float* xp = x + (size_t)(r0 + wave * 64 + t * 16 + m) * DIMS
                          + q * 32;
        float ss = 0.f;
#pragma unroll
        for (int d = 0; d < 8; ++d) {
            float4 v = *reinterpret_cast<const float4*>(xp + d * 4);
            int w0 = __builtin_amdgcn_cvt_pk_fp8_f32(v.x, v.y, 0, false);
            w0 = __builtin_amdgcn_cvt_pk_fp8_f32(v.z, v.w, w0, true);
            afrag[t].d[d] = w0;
            ss += v.x * v.x + v.y * v.y + v.z * v.z + v.w * v.w;
        }
        ss += __shfl_xor(ss, 16, 64);
        ss += __shfl_xor(ss, 32, 64);
        if (lane < 16) s_xn[wave * 64 + t * 16 + lane] = ss;
    }

    __builtin_amdgcn_s_waitcnt(0x0070);   // drain this wave's B loads
    __syncthreads();                      // all B/pn/xn visible; ONLY barrier

    // Barrier-free K-loop over the 32 resident pt-tiles.
    float runmin[4][4];
#pragma unroll
    for (int t = 0; t < 4; ++t)
#pragma unroll
        for (int r = 0; r < 4; ++r) runmin[t][r] = 1e30f;

#pragma unroll 2
    for (int tt = 0; tt < TPB; ++tt) {
        BFrag bf;
        bf.u4[0] = s_b[(tt * 2 + 0) * 64 + lane];   // ds_read_b128
        bf.u4[1] = s_b[(tt * 2 + 1) * 64 + lane];
        float pn = s_pn[tt * 16 + m];               // ds_read_b32
#pragma unroll
        for (int t = 0; t < 4; ++t) {
            f32x4 acc = {0.f, 0.f, 0.f, 0.f};
            acc = __builtin_amdgcn_mfma_scale_f32_16x16x128_f8f6f4(
                afrag[t].v, bf.v, acc, 0, 0, 0,
                0x7F7F7F7F, 0, 0x7F7F7F7F);
#pragma unroll
            for (int r = 0; r < 4; ++r)
                runmin[t][r] = fminf(runmin[t][r], fmaf(-2.f, acc[r], pn));
        }
    }

    // Lane reduce (min over 16 cols), finish d^2, combine via uint atomicMin.
    // C/D layout: col = m, row_local = t*16 + q*4 + r (within wave's 64).
#pragma unroll
    for (int t = 0; t < 4; ++t) {
#pragma unroll
        for (int r = 0; r < 4; ++r) {
            float v = runmin[t][r];
            v = fminf(v, __shfl_xor(v, 1, 64));
            v = fminf(v, __shfl_xor(v, 2, 64));
            v = fminf(v, __shfl_xor(v, 4, 64));
            v = fminf(v, __shfl_xor(v, 8, 64));
            if (m == 0) {
                int rl  = wave * 64 + t * 16 + q * 4 + r;
                float d2 = fmaxf(s_xn[rl] + v, 0.f);
                atomicMin(&minws[r0 + rl], __float_as_uint(d2));
            }
        }
    }
}

// --- finish kernel: sigmoid over the combined mins --------------------------
__global__ __launch_bounds__(256) void finish_kernel(
    const unsigned int* __restrict__ minws,
    const float* __restrict__ beta_raw, float* __restrict__ out)
{
    int i = blockIdx.x * 256 + threadIdx.x;
    float d2    = __uint_as_float(minws[i]);
    float br    = beta_raw[0];
    float beta  = log1pf(expf(br));
    float alpha = -beta * LOG1000F;
    float z = (d2 + alpha) / beta;
    out[i] = 1.f / (1.f + expf(-z));
}

extern "C" void kernel_launch(void* const* d_in, const int* in_sizes, int n_in,
                              void* d_out, int out_size, void* d_ws, size_t ws_size,
                              hipStream_t stream) {
    const float* x        = (const float*)d_in[0];
    const float* pts      = (const float*)d_in[1];
    const float* beta_raw = (const float*)d_in[2];
    float* out            = (float*)d_out;

    unsigned char* ptsf8 = (unsigned char*)d_ws;                     // 256 KB
    float* pnorm = (float*)((char*)d_ws + (size_t)NPTS * DIMS);      // 8 KB
    unsigned int* minws =
        (unsigned int*)((char*)d_ws + (size_t)NPTS * DIMS + NPTS * 4); // 256 KB

    prep_points_kernel<<<NPTS / 4, 256, 0, stream>>>(pts, ptsf8, pnorm, minws);
    distnet_main_kernel<<<(NROWS / RPB) * (NPTS / PPB), 256, 0, stream>>>(
        x, ptsf8, pnorm, minws);
    finish_kernel<<<NROWS / 256, 256, 0, stream>>>(minws, beta_raw, out);
}

// Round 10
// 109.011 us; speedup vs baseline: 1.2074x; 1.0309x over previous
//
#include <hip/hip_runtime.h>

// DistNet: out[n] = sigmoid((min_p ||x_n - p||^2 + alpha) / beta)
// beta = softplus(beta_raw), alpha = -beta*ln(1000)
// x: [65536,128] f32, points: [2048,128] f32, beta_raw: [1] f32, out: [65536] f32
//
// R10 design: R9's split-K structure (block = 256 rows x 512-pt quarter,
// B resident in LDS, ONE barrier, drain-free K-loop, uint atomicMin combine)
// with x PRE-CONVERTED to fp8 by an HBM-bound prep kernel. R9's 66 MB
// FETCH_SIZE was 4x-duplicated f32 x reads (split-K); fp8 x is 8 MB so the
// duplicated reads fit in L3 and the main kernel's A-load VALU disappears.
// fp8 e4m3 mfma_scale 16x16x128 (K=128 in one MFMA, scales=1.0).

#define NROWS 65536
#define NPTS  2048
#define DIMS  128
#define LOG1000F 6.9077542789816375f
#define RPB 256                  // rows per block
#define PPB 512                  // points per block
#define TPB (PPB / 16)           // 32 pt-tiles per block

typedef __attribute__((ext_vector_type(8))) int i32x8;
typedef __attribute__((ext_vector_type(4))) float f32x4;

union AFrag { uint4 u4[2]; i32x8 v; };
union BFrag { uint4 u4[2]; i32x8 v; };

// --- prep_x: x f32 -> fp8 e4m3 (8 MB), ||x||^2, minws init ------------------
// one wave per row; lane handles 2 features.
__global__ __launch_bounds__(256) void prep_x_kernel(
    const float* __restrict__ x, unsigned char* __restrict__ xf8,
    float* __restrict__ xnorm, unsigned int* __restrict__ minws)
{
    int tid  = threadIdx.x;
    int gid  = blockIdx.x * 256 + tid;
    if (gid < NROWS) minws[gid] = 0x7F800000u;   // +inf (re-init every launch)

    int lane = tid & 63;
    int w    = tid >> 6;
    int row  = blockIdx.x * 4 + w;
    const float2 v = *reinterpret_cast<const float2*>(
        x + (size_t)row * DIMS + lane * 2);
    int pk = __builtin_amdgcn_cvt_pk_fp8_f32(v.x, v.y, 0, false);
    *reinterpret_cast<unsigned short*>(xf8 + (size_t)row * DIMS + lane * 2) =
        (unsigned short)(pk & 0xFFFF);
    float ss = v.x * v.x + v.y * v.y;
    ss += __shfl_xor(ss, 1, 64);
    ss += __shfl_xor(ss, 2, 64);
    ss += __shfl_xor(ss, 4, 64);
    ss += __shfl_xor(ss, 8, 64);
    ss += __shfl_xor(ss, 16, 64);
    ss += __shfl_xor(ss, 32, 64);
    if (lane == 0) xnorm[row] = ss;
}

// --- prep_points: points f32 -> fp8 e4m3, ||p||^2 ---------------------------
__global__ __launch_bounds__(256) void prep_points_kernel(
    const float* __restrict__ pts, unsigned char* __restrict__ ptsf8,
    float* __restrict__ pnorm)
{
    int tid  = threadIdx.x;
    int lane = tid & 63;
    int w    = tid >> 6;
    int pt   = blockIdx.x * 4 + w;            // one wave per point
    const float2 v = *reinterpret_cast<const float2*>(
        pts + (size_t)pt * DIMS + lane * 2);
    int pk = __builtin_amdgcn_cvt_pk_fp8_f32(v.x, v.y, 0, false);
    *reinterpret_cast<unsigned short*>(ptsf8 + (size_t)pt * DIMS + lane * 2) =
        (unsigned short)(pk & 0xFFFF);
    float ss = v.x * v.x + v.y * v.y;
    ss += __shfl_xor(ss, 1, 64);
    ss += __shfl_xor(ss, 2, 64);
    ss += __shfl_xor(ss, 4, 64);
    ss += __shfl_xor(ss, 8, 64);
    ss += __shfl_xor(ss, 16, 64);
    ss += __shfl_xor(ss, 32, 64);
    if (lane == 0) pnorm[pt] = ss;
}

// --- main kernel ------------------------------------------------------------
// grid: (NROWS/RPB) * (NPTS/PPB) = 256 * 4 = 1024 blocks x 256 threads.
// block b: row-group b>>2 (ph adjacent -> x rows L3-shared), point-quarter b&3.
__global__ __launch_bounds__(256, 2) void distnet_main_kernel(
    const unsigned char* __restrict__ xf8, const unsigned char* __restrict__ ptsf8,
    const float* __restrict__ pnorm, const float* __restrict__ xnorm,
    unsigned int* __restrict__ minws)
{
    // B quarter in fragment order: 16B unit (tt*2+c)*64 + lane
    __shared__ uint4 s_b[PPB * DIMS / 16];   // 64 KB
    __shared__ float s_pn[PPB];              // 2 KB
    __shared__ float s_xn[RPB];              // 1 KB

    int tid  = threadIdx.x;
    int wave = tid >> 6;
    int lane = tid & 63;
    int m    = lane & 15;          // A row / B col (point) index
    int q    = lane >> 4;          // k-quad: lane covers k = q*32 .. q*32+31
    int rg   = blockIdx.x >> 2;
    int ph   = blockIdx.x & 3;
    int r0   = rg * RPB;
    int p0   = ph * PPB;

    // Prologue: whole B quarter into LDS. Wave w loads pt-tiles
    // tt in [w*8, w*8+8), halves c=0,1 -> 16 x 1KB global_load_lds.
    const unsigned char* gbase = ptsf8;
#pragma unroll
    for (int i = 0; i < 16; ++i) {
        int tt = wave * 8 + (i >> 1);
        int c  = i & 1;
        size_t pbyte = (size_t)(p0 + tt * 16 + m) * DIMS
                       + (size_t)q * 32 + (size_t)c * 16;
        const void* g = gbase + pbyte;
        void* l = (void*)&s_b[(tt * 2 + c) * 64];
        __builtin_amdgcn_global_load_lds(
            (const __attribute__((address_space(1))) unsigned int*)g,
            (__attribute__((address_space(3))) unsigned int*)l,
            16, 0, 0);
    }
    // s_pn (512 floats) and s_xn (256 floats), coalesced
    {
        float2 v = reinterpret_cast<const float2*>(pnorm + p0)[tid];
        reinterpret_cast<float2*>(s_pn)[tid] = v;
        s_xn[tid] = xnorm[r0 + tid];
    }

    // A fragments from fp8 x: 4 row-tiles (wave's 64 rows); lane holds
    // A[m][k=q*32+j], 32 B = 2 x uint4. No conversion VALU.
    AFrag afrag[4];
#pragma unroll
    for (int t = 0; t < 4; ++t) {
        const uint4* xp = reinterpret_cast<const uint4*>(
            xf8 + (size_t)(r0 + wave * 64 + t * 16 + m) * DIMS + q * 32);
        afrag[t].u4[0] = xp[0];
        afrag[t].u4[1] = xp[1];
    }

    __builtin_amdgcn_s_waitcnt(0x0070);   // drain this wave's B loads
    __syncthreads();                      // all B/pn/xn visible; ONLY barrier

    // Barrier-free K-loop over the 32 resident pt-tiles.
    float runmin[4][4];
#pragma unroll
    for (int t = 0; t < 4; ++t)
#pragma unroll
        for (int r = 0; r < 4; ++r) runmin[t][r] = 1e30f;

#pragma unroll 2
    for (int tt = 0; tt < TPB; ++tt) {
        BFrag bf;
        bf.u4[0] = s_b[(tt * 2 + 0) * 64 + lane];   // ds_read_b128
        bf.u4[1] = s_b[(tt * 2 + 1) * 64 + lane];
        float pn = s_pn[tt * 16 + m];               // ds_read_b32
#pragma unroll
        for (int t = 0; t < 4; ++t) {
            f32x4 acc = {0.f, 0.f, 0.f, 0.f};
            acc = __builtin_amdgcn_mfma_scale_f32_16x16x128_f8f6f4(
                afrag[t].v, bf.v, acc, 0, 0, 0,
                0x7F7F7F7F, 0, 0x7F7F7F7F);
#pragma unroll
            for (int r = 0; r < 4; ++r)
                runmin[t][r] = fminf(runmin[t][r], fmaf(-2.f, acc[r], pn));
        }
    }

    // Lane reduce (min over 16 cols), finish d^2, combine via uint atomicMin.
    // C/D layout: col = m, row_local = t*16 + q*4 + r (within wave's 64).
#pragma unroll
    for (int t = 0; t < 4; ++t) {
#pragma unroll
        for (int r = 0; r < 4; ++r) {
            float v = runmin[t][r];
            v = fminf(v, __shfl_xor(v, 1, 64));
            v = fminf(v, __shfl_xor(v, 2, 64));
            v = fminf(v, __shfl_xor(v, 4, 64));
            v = fminf(v, __shfl_xor(v, 8, 64));
            if (m == 0) {
                int rl  = wave * 64 + t * 16 + q * 4 + r;
                float d2 = fmaxf(s_xn[rl] + v, 0.f);
                atomicMin(&minws[r0 + rl], __float_as_uint(d2));
            }
        }
    }
}

// --- finish kernel: sigmoid over the combined mins --------------------------
__global__ __launch_bounds__(256) void finish_kernel(
    const unsigned int* __restrict__ minws,
    const float* __restrict__ beta_raw, float* __restrict__ out)
{
    int i = blockIdx.x * 256 + threadIdx.x;
    float d2    = __uint_as_float(minws[i]);
    float br    = beta_raw[0];
    float beta  = log1pf(expf(br));
    float alpha = -beta * LOG1000F;
    float z = (d2 + alpha) / beta;
    out[i] = 1.f / (1.f + expf(-z));
}

extern "C" void kernel_launch(void* const* d_in, const int* in_sizes, int n_in,
                              void* d_out, int out_size, void* d_ws, size_t ws_size,
                              hipStream_t stream) {
    const float* x        = (const float*)d_in[0];
    const float* pts      = (const float*)d_in[1];
    const float* beta_raw = (const float*)d_in[2];
    float* out            = (float*)d_out;

    char* ws = (char*)d_ws;
    unsigned char* ptsf8 = (unsigned char*)ws;                  // 256 KB
    float* pnorm  = (float*)(ws + 256 * 1024);                  // 8 KB
    unsigned int* minws = (unsigned int*)(ws + 264 * 1024);     // 256 KB
    unsigned char* xf8  = (unsigned char*)(ws + 520 * 1024);    // 8 MB
    float* xnorm  = (float*)(ws + 520 * 1024 + (size_t)NROWS * DIMS); // 256 KB

    prep_x_kernel<<<NROWS / 4, 256, 0, stream>>>(x, xf8, xnorm, minws);
    prep_points_kernel<<<NPTS / 4, 256, 0, stream>>>(pts, ptsf8, pnorm);
    distnet_main_kernel<<<(NROWS / RPB) * (NPTS / PPB), 256, 0, stream>>>(
        xf8, ptsf8, pnorm, xnorm, minws);
    finish_kernel<<<NROWS / 256, 256, 0, stream>>>(minws, beta_raw, out);
}

// Round 11
// 108.480 us; speedup vs baseline: 1.2133x; 1.0049x over previous
//
#include <hip/hip_runtime.h>

// DistNet: out[n] = sigmoid((min_p ||x_n - p||^2 + alpha) / beta)
// beta = softplus(beta_raw), alpha = -beta*ln(1000)
// x: [65536,128] f32, points: [2048,128] f32, beta_raw: [1] f32, out: [65536] f32
//
// R11 design: R10's split-K structure (B resident in LDS, ONE barrier,
// drain-free K-loop, fp8 x+p, uint atomicMin combine) with the point
// partition halved to PPB=256 -> 34 KB LDS -> 4 blocks/CU = 4 waves/SIMD.
// R3-R10 all plateaued at main ~40 us with Occupancy ~17-22% (~1.5 waves/
// SIMD): the K-loop is latency-serialized (~300 cyc exposed per MFMA unit)
// and nothing covers it. This round changes ONLY the TLP.

#define NROWS 65536
#define NPTS  2048
#define DIMS  128
#define LOG1000F 6.9077542789816375f
#define RPB 256                  // rows per block
#define PPB 256                  // points per block
#define TPB (PPB / 16)           // 16 pt-tiles per block

typedef __attribute__((ext_vector_type(8))) int i32x8;
typedef __attribute__((ext_vector_type(4))) float f32x4;

union AFrag { uint4 u4[2]; i32x8 v; };
union BFrag { uint4 u4[2]; i32x8 v; };

// --- prep_x: x f32 -> fp8 e4m3 (8 MB), ||x||^2, minws init ------------------
__global__ __launch_bounds__(256) void prep_x_kernel(
    const float* __restrict__ x, unsigned char* __restrict__ xf8,
    float* __restrict__ xnorm, unsigned int* __restrict__ minws)
{
    int tid  = threadIdx.x;
    int gid  = blockIdx.x * 256 + tid;
    if (gid < NROWS) minws[gid] = 0x7F800000u;   // +inf (re-init every launch)

    int lane = tid & 63;
    int w    = tid >> 6;
    int row  = blockIdx.x * 4 + w;
    const float2 v = *reinterpret_cast<const float2*>(
        x + (size_t)row * DIMS + lane * 2);
    int pk = __builtin_amdgcn_cvt_pk_fp8_f32(v.x, v.y, 0, false);
    *reinterpret_cast<unsigned short*>(xf8 + (size_t)row * DIMS + lane * 2) =
        (unsigned short)(pk & 0xFFFF);
    float ss = v.x * v.x + v.y * v.y;
    ss += __shfl_xor(ss, 1, 64);
    ss += __shfl_xor(ss, 2, 64);
    ss += __shfl_xor(ss, 4, 64);
    ss += __shfl_xor(ss, 8, 64);
    ss += __shfl_xor(ss, 16, 64);
    ss += __shfl_xor(ss, 32, 64);
    if (lane == 0) xnorm[row] = ss;
}

// --- prep_points: points f32 -> fp8 e4m3, ||p||^2 ---------------------------
__global__ __launch_bounds__(256) void prep_points_kernel(
    const float* __restrict__ pts, unsigned char* __restrict__ ptsf8,
    float* __restrict__ pnorm)
{
    int tid  = threadIdx.x;
    int lane = tid & 63;
    int w    = tid >> 6;
    int pt   = blockIdx.x * 4 + w;            // one wave per point
    const float2 v = *reinterpret_cast<const float2*>(
        pts + (size_t)pt * DIMS + lane * 2);
    int pk = __builtin_amdgcn_cvt_pk_fp8_f32(v.x, v.y, 0, false);
    *reinterpret_cast<unsigned short*>(ptsf8 + (size_t)pt * DIMS + lane * 2) =
        (unsigned short)(pk & 0xFFFF);
    float ss = v.x * v.x + v.y * v.y;
    ss += __shfl_xor(ss, 1, 64);
    ss += __shfl_xor(ss, 2, 64);
    ss += __shfl_xor(ss, 4, 64);
    ss += __shfl_xor(ss, 8, 64);
    ss += __shfl_xor(ss, 16, 64);
    ss += __shfl_xor(ss, 32, 64);
    if (lane == 0) pnorm[pt] = ss;
}

// --- main kernel ------------------------------------------------------------
// grid: (NROWS/RPB) * (NPTS/PPB) = 256 * 8 = 2048 blocks x 256 threads.
// block b: row-group b>>3 (8 point-eighths adjacent -> xf8 L3-shared), b&7.
__global__ __launch_bounds__(256, 4) void distnet_main_kernel(
    const unsigned char* __restrict__ xf8, const unsigned char* __restrict__ ptsf8,
    const float* __restrict__ pnorm, const float* __restrict__ xnorm,
    unsigned int* __restrict__ minws)
{
    // B eighth in fragment order: 16B unit (tt*2+c)*64 + lane
    __shared__ uint4 s_b[PPB * DIMS / 16];   // 32 KB
    __shared__ float s_pn[PPB];              // 1 KB
    __shared__ float s_xn[RPB];              // 1 KB

    int tid  = threadIdx.x;
    int wave = tid >> 6;
    int lane = tid & 63;
    int m    = lane & 15;          // A row / B col (point) index
    int q    = lane >> 4;          // k-quad: lane covers k = q*32 .. q*32+31
    int rg   = blockIdx.x >> 3;
    int ph   = blockIdx.x & 7;
    int r0   = rg * RPB;
    int p0   = ph * PPB;

    // Prologue: whole B eighth into LDS. Wave w loads pt-tiles
    // tt in [w*4, w*4+4), halves c=0,1 -> 8 x 1KB global_load_lds.
    const unsigned char* gbase = ptsf8;
#pragma unroll
    for (int i = 0; i < 8; ++i) {
        int tt = wave * 4 + (i >> 1);
        int c  = i & 1;
        size_t pbyte = (size_t)(p0 + tt * 16 + m) * DIMS
                       + (size_t)q * 32 + (size_t)c * 16;
        const void* g = gbase + pbyte;
        void* l = (void*)&s_b[(tt * 2 + c) * 64];
        __builtin_amdgcn_global_load_lds(
            (const __attribute__((address_space(1))) unsigned int*)g,
            (__attribute__((address_space(3))) unsigned int*)l,
            16, 0, 0);
    }
    // s_pn (256 floats) and s_xn (256 floats), coalesced
    s_pn[tid] = pnorm[p0 + tid];
    s_xn[tid] = xnorm[r0 + tid];

    // A fragments from fp8 x: 4 row-tiles (wave's 64 rows); lane holds
    // A[m][k=q*32+j], 32 B = 2 x uint4. No conversion VALU.
    AFrag afrag[4];
#pragma unroll
    for (int t = 0; t < 4; ++t) {
        const uint4* xp = reinterpret_cast<const uint4*>(
            xf8 + (size_t)(r0 + wave * 64 + t * 16 + m) * DIMS + q * 32);
        afrag[t].u4[0] = xp[0];
        afrag[t].u4[1] = xp[1];
    }

    __builtin_amdgcn_s_waitcnt(0x0070);   // drain this wave's B loads
    __syncthreads();                      // all B/pn/xn visible; ONLY barrier

    // Barrier-free K-loop over the 16 resident pt-tiles.
    float runmin[4][4];
#pragma unroll
    for (int t = 0; t < 4; ++t)
#pragma unroll
        for (int r = 0; r < 4; ++r) runmin[t][r] = 1e30f;

#pragma unroll 4
    for (int tt = 0; tt < TPB; ++tt) {
        BFrag bf;
        bf.u4[0] = s_b[(tt * 2 + 0) * 64 + lane];   // ds_read_b128
        bf.u4[1] = s_b[(tt * 2 + 1) * 64 + lane];
        float pn = s_pn[tt * 16 + m];               // ds_read_b32
#pragma unroll
        for (int t = 0; t < 4; ++t) {
            f32x4 acc = {0.f, 0.f, 0.f, 0.f};
            acc = __builtin_amdgcn_mfma_scale_f32_16x16x128_f8f6f4(
                afrag[t].v, bf.v, acc, 0, 0, 0,
                0x7F7F7F7F, 0, 0x7F7F7F7F);
#pragma unroll
            for (int r = 0; r < 4; ++r)
                runmin[t][r] = fminf(runmin[t][r], fmaf(-2.f, acc[r], pn));
        }
    }

    // Lane reduce (min over 16 cols), finish d^2, combine via uint atomicMin.
    // C/D layout: col = m, row_local = t*16 + q*4 + r (within wave's 64).
#pragma unroll
    for (int t = 0; t < 4; ++t) {
#pragma unroll
        for (int r = 0; r < 4; ++r) {
            float v = runmin[t][r];
            v = fminf(v, __shfl_xor(v, 1, 64));
            v = fminf(v, __shfl_xor(v, 2, 64));
            v = fminf(v, __shfl_xor(v, 4, 64));
            v = fminf(v, __shfl_xor(v, 8, 64));
            if (m == 0) {
                int rl  = wave * 64 + t * 16 + q * 4 + r;
                float d2 = fmaxf(s_xn[rl] + v, 0.f);
                atomicMin(&minws[r0 + rl], __float_as_uint(d2));
            }
        }
    }
}

// --- finish kernel: sigmoid over the combined mins --------------------------
__global__ __launch_bounds__(256) void finish_kernel(
    const unsigned int* __restrict__ minws,
    const float* __restrict__ beta_raw, float* __restrict__ out)
{
    int i = blockIdx.x * 256 + threadIdx.x;
    float d2    = __uint_as_float(minws[i]);
    float br    = beta_raw[0];
    float beta  = log1pf(expf(br));
    float alpha = -beta * LOG1000F;
    float z = (d2 + alpha) / beta;
    out[i] = 1.f / (1.f + expf(-z));
}

extern "C" void kernel_launch(void* const* d_in, const int* in_sizes, int n_in,
                              void* d_out, int out_size, void* d_ws, size_t ws_size,
                              hipStream_t stream) {
    const float* x        = (const float*)d_in[0];
    const float* pts      = (const float*)d_in[1];
    const float* beta_raw = (const float*)d_in[2];
    float* out            = (float*)d_out;

    char* ws = (char*)d_ws;
    unsigned char* ptsf8 = (unsigned char*)ws;                  // 256 KB
    float* pnorm  = (float*)(ws + 256 * 1024);                  // 8 KB
    unsigned int* minws = (unsigned int*)(ws + 264 * 1024);     // 256 KB
    unsigned char* xf8  = (unsigned char*)(ws + 520 * 1024);    // 8 MB
    float* xnorm  = (float*)(ws + 520 * 1024 + (size_t)NROWS * DIMS); // 256 KB

    prep_x_kernel<<<NROWS / 4, 256, 0, stream>>>(x, xf8, xnorm, minws);
    prep_points_kernel<<<NPTS / 4, 256, 0, stream>>>(pts, ptsf8, pnorm);
    distnet_main_kernel<<<(NROWS / RPB) * (NPTS / PPB), 256, 0, stream>>>(
        xf8, ptsf8, pnorm, xnorm, minws);
    finish_kernel<<<NROWS / 256, 256, 0, stream>>>(minws, beta_raw, out);
}